// Round 13
// baseline (3815.963 us; speedup 1.0000x reference)
//
#include <hip/hip_runtime.h>
#include <math.h>

// ESN: 512 sequential steps of h = tanh([h | x_t] @ [W_hh|W_ih]^T + b)
// T=512, B=64, I=128, H=1024, K' = 1152.
//
// R17 (from R12 @ 2.77 ms; R16 neutral -> wait is latency, not contention):
// two independent chains per CU.
//  * Batch rows are INDEPENDENT recurrences (row b depends only on row b).
//    Split bgrps: 512 WGs = 16 bgrps x 32 jblks, 4 rows/bgrp, 2 WGs/CU
//    (LDS ~29 KB, NB=4). Round-robin dispatch co-locates (wg, wg+256) =
//    DIFFERENT bgrps = decoupled chains at uncorrelated phases: while one
//    WG waits on its sentinel poll, the other's waves use the SIMDs.
//  * Per-thread W footprint unchanged (18 float4); wg and wg+256 share the
//    same jblk -> same W slice in the XCD L2 (reuse doubles).
//  * Per-chain protocol byte-equivalent to R12: sentinel sync (out
//    pre-poisoned 0x7F7F7F7F, data IS the flag, fire-and-forget sc0sc1
//    dwordx4 stores), wave-wide 4-producer poll, wave-private k-slice
//    staging (no pre-FMA barrier), one __syncthreads/step, parity-dbuf
//    red[], W+bias VGPR-resident, x prefetch.

#define T_STEPS 512
#define BATCH   64
#define HDIM    1024
#define IDIM    128
#define KDIM    1152
#define NWG     512
#define NB      4
#define POISON  0x7F7F7F7Fu

typedef float f32x4_t __attribute__((ext_vector_type(4)));

// 2 x 16B coherence-point loads from 2 addresses, single drain.
__device__ __forceinline__ void sc_load2x4(const float* p0, const float* p1,
                                           float4& a, float4& b) {
    asm volatile(
        "global_load_dwordx4 %0, %2, off sc0 sc1\n\t"
        "global_load_dwordx4 %1, %3, off sc0 sc1\n\t"
        "s_waitcnt vmcnt(0)"
        : "=&v"(a), "=&v"(b)
        : "v"(p0), "v"(p1)
        : "memory");
}

// 16B write-through store (no drain: visibility rides the write; consumers
// poll the data itself)
__device__ __forceinline__ void sc_store4_nodrain(float* p, float4 v) {
    f32x4_t t;
    t.x = v.x; t.y = v.y; t.z = v.z; t.w = v.w;
    asm volatile("global_store_dwordx4 %0, %1, off sc0 sc1"
                 :: "v"(p), "v"(t) : "memory");
}

__device__ __forceinline__ unsigned chk4(float4 v) {
    return (unsigned)((__float_as_uint(v.x) == POISON) |
                      (__float_as_uint(v.y) == POISON) |
                      (__float_as_uint(v.z) == POISON) |
                      (__float_as_uint(v.w) == POISON));
}

// src[R][C] -> dst[C][R], 64x64 LDS tiles, grid = (C/64)*(R/64), 256 thr
__global__ void transpose_f32(const float* __restrict__ src, float* __restrict__ dst,
                              int R, int C) {
    __shared__ float tile[64][65];
    const int tcol = threadIdx.x & 63;
    const int trow = threadIdx.x >> 6;
    const int nbx = C >> 6;
    const int bx = blockIdx.x % nbx;
    const int by = blockIdx.x / nbx;
    const int c0 = bx << 6, r0 = by << 6;
    for (int i = trow; i < 64; i += 4)
        tile[i][tcol] = src[(size_t)(r0 + i) * C + c0 + tcol];
    __syncthreads();
    for (int i = trow; i < 64; i += 4)
        dst[(size_t)(c0 + i) * R + r0 + tcol] = tile[tcol][i];
}

__global__ __launch_bounds__(512) void esn_persistent(
    const float* __restrict__ x,     // [512][64][128]
    const float* __restrict__ h0,    // [64][1024]
    const float* __restrict__ WT,    // [1152][1024]
    const float* __restrict__ bias,  // [1024]
    float* __restrict__ out,         // [512][64][1024] (pre-poisoned)
    float* __restrict__ hfin)        // [64][1024]
{
    const int tid  = threadIdx.x;
    const int wg   = blockIdx.x;
    const int wave = tid >> 6;                       // 0..7 (k-slice; 0-3 also epi row)
    const int lane = tid & 63;
    const int jq   = lane & 7;                       // 4 j each -> 32 j
    const int ksub = lane >> 3;                      // 0..7 k-interleave
    const int jblk = ((wg & 7) << 2) | ((wg >> 3) & 3);  // XCD owns 4 jblks
    const int bgrp = wg >> 5;                            // 0..15
    const int b0   = bgrp << 2;                          // 4 rows per bgrp
    const int j0   = (jblk << 5) + (jq << 2);
    const int krec = wave << 7;                      // recurrent k base (128/wave)
    const int kx   = HDIM + (wave << 4) + (ksub << 1);  // x-part rows (2 each)

    // wave-private staging blocks (4 rows)
    __shared__ float  ht2[8 * 512];                  // [wave][4 rows][128 k] 16KB
    __shared__ float  htx[8 * 64];                   // [wave][4 rows][16 xk]  2KB
    __shared__ float4 red[2][8 * 8 * 5];             // parity-dbuf reduce    10KB

    // ---- hoist all 18 W float4 loads for ALL 512 steps (72 VGPRs) ----
    float4 Wv[18];
    {
        const float* wp = WT + (size_t)krec * HDIM + j0;
        #pragma unroll
        for (int i = 0; i < 4; ++i) {
            const int kk = ((i << 3) + ksub) << 2;      // 0..124 step 4
            const float* wk = wp + (size_t)kk * HDIM;
            Wv[i * 4 + 0] = *(const float4*)(wk);
            Wv[i * 4 + 1] = *(const float4*)(wk + HDIM);
            Wv[i * 4 + 2] = *(const float4*)(wk + 2 * HDIM);
            Wv[i * 4 + 3] = *(const float4*)(wk + 3 * HDIM);
        }
        const float* wkx = WT + (size_t)kx * HDIM + j0;
        Wv[16] = *(const float4*)(wkx);
        Wv[17] = *(const float4*)(wkx + HDIM);
    }

    // ---- epilogue constants: lanes 0-7 of waves 0-3 handle row b0+wave ----
    float4 b4 = make_float4(0.f, 0.f, 0.f, 0.f);
    int jj = 0;
    if (lane < 8) {
        jj = (jblk << 5) + (lane << 2);
        b4 = *(const float4*)(bias + jj);
    }

    // ---- staging lane maps (4 rows: lane covers rows sbb, sbb+2) ----
    const int sbb = lane >> 5;                 // row parity (0/1)
    const int sko = (lane & 31) << 2;          // k-offset within slice
    float* hdst = ht2 + (wave << 9) + (sbb << 7) + sko;  // row sbb; +256 row sbb+2
    const int xr = lane >> 4;                  // x row 0..3
    const int xco = lane & 15;                 // x col within 16-slice
    float* xdst = htx + (wave << 6) + (xr << 4) + xco;
    const float* hb = ht2 + (wave << 9);
    const float* xb = htx + (wave << 6);

    // ---- prefetch x slice for t=0 (plain cached load, x read-only) ----
    float xv = x[(size_t)(b0 + xr) * IDIM + (wave << 4) + xco];

    for (int t = 0; t < T_STEPS; ++t) {
        // ---- stage this wave's k-slice of 4 rows into wave-private LDS ----
        *xdst = xv;
        if (t == 0) {
            const float* p = h0 + (size_t)(b0 + sbb) * HDIM + krec + sko;
            *(float4*)(hdst)       = *(const float4*)(p);
            *(float4*)(hdst + 256) = *(const float4*)(p + 2 * HDIM);
        } else {
            // sentinel poll: data IS the flag (wave-wide over 4 producers)
            const float* p = out + ((size_t)(t - 1) * BATCH + b0 + sbb) * HDIM
                             + krec + sko;
            float4 a, b;
            do {
                sc_load2x4(p, p + 2 * HDIM, a, b);
            } while (__any((int)(chk4(a) | chk4(b))));
            *(float4*)(hdst)       = a;
            *(float4*)(hdst + 256) = b;
        }
        // NO __syncthreads: staged data is wave-private.

        // prefetch next x slice; latency hides under the FMA phase
        if (t + 1 < T_STEPS)
            xv = x[((size_t)(t + 1) * BATCH + b0 + xr) * IDIM + (wave << 4) + xco];

        // ---- FMA: acc[b] over this thread's k (W in registers) ----
        float4 acc[NB];
        #pragma unroll
        for (int bb = 0; bb < NB; ++bb) acc[bb] = make_float4(0.f, 0.f, 0.f, 0.f);

        #pragma unroll
        for (int i = 0; i < 4; ++i) {
            const int ko = ((i << 3) + ksub) << 2;       // 0..124 step 4
            const float4 w0 = Wv[i * 4 + 0], w1 = Wv[i * 4 + 1];
            const float4 w2 = Wv[i * 4 + 2], w3 = Wv[i * 4 + 3];
            #pragma unroll
            for (int bb = 0; bb < NB; ++bb) {
                float4 h4 = *(const float4*)(hb + (bb << 7) + ko);
                acc[bb].x = fmaf(w0.x, h4.x, acc[bb].x);
                acc[bb].y = fmaf(w0.y, h4.x, acc[bb].y);
                acc[bb].z = fmaf(w0.z, h4.x, acc[bb].z);
                acc[bb].w = fmaf(w0.w, h4.x, acc[bb].w);
                acc[bb].x = fmaf(w1.x, h4.y, acc[bb].x);
                acc[bb].y = fmaf(w1.y, h4.y, acc[bb].y);
                acc[bb].z = fmaf(w1.z, h4.y, acc[bb].z);
                acc[bb].w = fmaf(w1.w, h4.y, acc[bb].w);
                acc[bb].x = fmaf(w2.x, h4.z, acc[bb].x);
                acc[bb].y = fmaf(w2.y, h4.z, acc[bb].y);
                acc[bb].z = fmaf(w2.z, h4.z, acc[bb].z);
                acc[bb].w = fmaf(w2.w, h4.z, acc[bb].w);
                acc[bb].x = fmaf(w3.x, h4.w, acc[bb].x);
                acc[bb].y = fmaf(w3.y, h4.w, acc[bb].y);
                acc[bb].z = fmaf(w3.z, h4.w, acc[bb].z);
                acc[bb].w = fmaf(w3.w, h4.w, acc[bb].w);
            }
        }
        // x tail: 2 k per thread
        #pragma unroll
        for (int bb = 0; bb < NB; ++bb) {
            float2 hx = *(const float2*)(xb + (bb << 4) + (ksub << 1));
            acc[bb].x = fmaf(Wv[16].x, hx.x, acc[bb].x);
            acc[bb].y = fmaf(Wv[16].y, hx.x, acc[bb].y);
            acc[bb].z = fmaf(Wv[16].z, hx.x, acc[bb].z);
            acc[bb].w = fmaf(Wv[16].w, hx.x, acc[bb].w);
            acc[bb].x = fmaf(Wv[17].x, hx.y, acc[bb].x);
            acc[bb].y = fmaf(Wv[17].y, hx.y, acc[bb].y);
            acc[bb].z = fmaf(Wv[17].z, hx.y, acc[bb].z);
            acc[bb].w = fmaf(Wv[17].w, hx.y, acc[bb].w);
        }

        // ---- reduce over ksub (lane bits 3,4,5) ----
        #pragma unroll
        for (int bb = 0; bb < NB; ++bb) {
            acc[bb].x += __shfl_xor(acc[bb].x, 8);
            acc[bb].y += __shfl_xor(acc[bb].y, 8);
            acc[bb].z += __shfl_xor(acc[bb].z, 8);
            acc[bb].w += __shfl_xor(acc[bb].w, 8);
            acc[bb].x += __shfl_xor(acc[bb].x, 16);
            acc[bb].y += __shfl_xor(acc[bb].y, 16);
            acc[bb].z += __shfl_xor(acc[bb].z, 16);
            acc[bb].w += __shfl_xor(acc[bb].w, 16);
            acc[bb].x += __shfl_xor(acc[bb].x, 32);
            acc[bb].y += __shfl_xor(acc[bb].y, 32);
            acc[bb].z += __shfl_xor(acc[bb].z, 32);
            acc[bb].w += __shfl_xor(acc[bb].w, 32);
        }
        if (ksub == 0) {
            #pragma unroll
            for (int bb = 0; bb < NB; ++bb)
                red[t & 1][((wave << 3) + jq) * 5 + bb] = acc[bb];
        }
        __syncthreads();                               // red[t&1] complete

        // ---- epilogue: waves 0-3, lanes 0-7 -> row b0+wave ----
        if (wave < 4 && lane < 8) {
            float4 s = make_float4(0.f, 0.f, 0.f, 0.f);
            #pragma unroll
            for (int w = 0; w < 8; ++w) {
                float4 r = red[t & 1][((w << 3) + lane) * 5 + wave];
                s.x += r.x; s.y += r.y; s.z += r.z; s.w += r.w;
            }
            float4 o;
            o.x = tanhf(s.x + b4.x);
            o.y = tanhf(s.y + b4.y);
            o.z = tanhf(s.z + b4.z);
            o.w = tanhf(s.w + b4.w);
            // fire-and-forget write-through: the store itself is the signal
            sc_store4_nodrain(out + ((size_t)t * BATCH + b0 + wave) * HDIM + jj, o);
            if (t == T_STEPS - 1)
                *(float4*)(hfin + (size_t)(b0 + wave) * HDIM + jj) = o;
        }
    }
}

extern "C" void kernel_launch(void* const* d_in, const int* in_sizes, int n_in,
                              void* d_out, int out_size, void* d_ws, size_t ws_size,
                              hipStream_t stream) {
    const float* x    = (const float*)d_in[0];
    const float* h0   = (const float*)d_in[1];
    const float* w_ih = (const float*)d_in[2];   // [1024][128]
    const float* w_hh = (const float*)d_in[3];   // [1024][1024]
    const float* bias = (const float*)d_in[4];   // [1024]
    float* out = (float*)d_out;

    char* ws = (char*)d_ws;
    float* WT = (float*)ws;                      // [1152][1024] = 4.72 MB

    // poison the polled region: byte 0x7F -> dword 0x7F7F7F7F = 3.4e38,
    // unreachable by tanh. Stream-ordered; re-arms on every replay.
    (void)hipMemsetAsync(out, 0x7F,
                         (size_t)T_STEPS * BATCH * HDIM * sizeof(float), stream);
    transpose_f32<<<256, 256, 0, stream>>>(w_hh, WT, HDIM, HDIM);
    transpose_f32<<<32, 256, 0, stream>>>(w_ih, WT + (size_t)HDIM * HDIM, HDIM, IDIM);
    esn_persistent<<<NWG, 512, 0, stream>>>(x, h0, WT, bias,
                                            out, out + (size_t)T_STEPS * BATCH * HDIM);
}

// Round 14
// 2553.568 us; speedup vs baseline: 1.4944x; 1.4944x over previous
//
#include <hip/hip_runtime.h>
#include <math.h>

// ESN: 512 sequential steps of h = tanh([h | x_t] @ [W_hh|W_ih]^T + b)
// T=512, B=64, I=128, H=1024, K' = 1152.
//
// R18 (from R12 @ 2.77 ms; R17's 512-WG split ran SERIALLY -- occupancy
// stayed 8 waves/CU, halves at 3.7us/step with 4-row chains):
// two independent 4-row chains INTERLEAVED INSIDE each WG.
//  * 256 WGs, 1/CU (no co-residency needed). Chain A = rows b0..b0+3,
//    chain B = rows b0+4..b0+7 -- independent recurrences. Per period:
//    pollA -> FMA_A -> redA -> sync -> epiA/publishA ->
//    pollB -> FMA_B -> redB -> sync -> epiB/publishB.
//    A's publish->next-poll gap is filled by B's whole phase (and vice
//    versa): exposed wait = max(0, delta - other_phase). R17's serial
//    halves measured delta + c_phase = 3.7us for a 4-row phase; interleaved,
//    one period advances ALL 8 rows -> ~3.7-4.0us per full step.
//  * Race-freedom with only 2 syncthreads/period and NO parity dbuf:
//    redA(t+1) writes happen after syncB(t) (program order: ...epiB(t) is
//    before syncA(t+1)? no: write-redA(t+1) comes after the wave passes
//    syncB(t), and syncB(t) requires all waves' epiA(t) reads done).
//    Symmetric for redB via syncA(t+1). ht/htx are wave-private per chain.
//  * Per-chain protocol byte-equivalent R12 (proven): sentinel sync (out
//    pre-poisoned 0x7F7F7F7F, data IS the flag, fire-and-forget sc0sc1
//    16B stores, no flags/no drain), wave-wide poll, wave-private k-slice
//    staging, W (18 float4) + bias VGPR-resident, x prefetch.

#define T_STEPS 512
#define BATCH   64
#define HDIM    1024
#define IDIM    128
#define KDIM    1152
#define NWG     256
#define NB      4
#define POISON  0x7F7F7F7Fu

typedef float f32x4_t __attribute__((ext_vector_type(4)));

// 2 x 16B coherence-point loads from 2 addresses, single drain.
__device__ __forceinline__ void sc_load2x4(const float* p0, const float* p1,
                                           float4& a, float4& b) {
    asm volatile(
        "global_load_dwordx4 %0, %2, off sc0 sc1\n\t"
        "global_load_dwordx4 %1, %3, off sc0 sc1\n\t"
        "s_waitcnt vmcnt(0)"
        : "=&v"(a), "=&v"(b)
        : "v"(p0), "v"(p1)
        : "memory");
}

// 16B write-through store (no drain: visibility rides the write; consumers
// poll the data itself)
__device__ __forceinline__ void sc_store4_nodrain(float* p, float4 v) {
    f32x4_t t;
    t.x = v.x; t.y = v.y; t.z = v.z; t.w = v.w;
    asm volatile("global_store_dwordx4 %0, %1, off sc0 sc1"
                 :: "v"(p), "v"(t) : "memory");
}

__device__ __forceinline__ unsigned chk4(float4 v) {
    return (unsigned)((__float_as_uint(v.x) == POISON) |
                      (__float_as_uint(v.y) == POISON) |
                      (__float_as_uint(v.z) == POISON) |
                      (__float_as_uint(v.w) == POISON));
}

// src[R][C] -> dst[C][R], 64x64 LDS tiles, grid = (C/64)*(R/64), 256 thr
__global__ void transpose_f32(const float* __restrict__ src, float* __restrict__ dst,
                              int R, int C) {
    __shared__ float tile[64][65];
    const int tcol = threadIdx.x & 63;
    const int trow = threadIdx.x >> 6;
    const int nbx = C >> 6;
    const int bx = blockIdx.x % nbx;
    const int by = blockIdx.x / nbx;
    const int c0 = bx << 6, r0 = by << 6;
    for (int i = trow; i < 64; i += 4)
        tile[i][tcol] = src[(size_t)(r0 + i) * C + c0 + tcol];
    __syncthreads();
    for (int i = trow; i < 64; i += 4)
        dst[(size_t)(c0 + i) * R + r0 + tcol] = tile[tcol][i];
}

__global__ __launch_bounds__(512) void esn_persistent(
    const float* __restrict__ x,     // [512][64][128]
    const float* __restrict__ h0,    // [64][1024]
    const float* __restrict__ WT,    // [1152][1024]
    const float* __restrict__ bias,  // [1024]
    float* __restrict__ out,         // [512][64][1024] (pre-poisoned)
    float* __restrict__ hfin)        // [64][1024]
{
    const int tid  = threadIdx.x;
    const int wg   = blockIdx.x;
    const int wave = tid >> 6;                       // 0..7 (k-slice; 0-3 epi row)
    const int lane = tid & 63;
    const int jq   = lane & 7;                       // 4 j each -> 32 j
    const int ksub = lane >> 3;                      // 0..7 k-interleave
    const int jblk = ((wg & 7) << 2) | ((wg >> 3) & 3);  // XCD owns 4 jblks
    const int bgrp = wg >> 5;                            // 0..7
    const int b0   = bgrp << 3;                          // 8 rows: A=0..3, B=4..7
    const int j0   = (jblk << 5) + (jq << 2);
    const int krec = wave << 7;                      // recurrent k base (128/wave)
    const int kx   = HDIM + (wave << 4) + (ksub << 1);  // x-part rows (2 each)

    // chain-private staging blocks
    __shared__ float  htA[8 * 512];                  // [wave][4 rows][128 k] 16KB
    __shared__ float  htB[8 * 512];                  // 16KB
    __shared__ float  hxA[8 * 64];                   // [wave][4 rows][16 xk]  2KB
    __shared__ float  hxB[8 * 64];                   //  2KB
    __shared__ float4 redA[8 * 8 * 5];               // [w][jq] stride 5       5KB
    __shared__ float4 redB[8 * 8 * 5];               //  5KB

    // ---- hoist all 18 W float4 loads for ALL 512 steps (72 VGPRs) ----
    float4 Wv[18];
    {
        const float* wp = WT + (size_t)krec * HDIM + j0;
        #pragma unroll
        for (int i = 0; i < 4; ++i) {
            const int kk = ((i << 3) + ksub) << 2;      // 0..124 step 4
            const float* wk = wp + (size_t)kk * HDIM;
            Wv[i * 4 + 0] = *(const float4*)(wk);
            Wv[i * 4 + 1] = *(const float4*)(wk + HDIM);
            Wv[i * 4 + 2] = *(const float4*)(wk + 2 * HDIM);
            Wv[i * 4 + 3] = *(const float4*)(wk + 3 * HDIM);
        }
        const float* wkx = WT + (size_t)kx * HDIM + j0;
        Wv[16] = *(const float4*)(wkx);
        Wv[17] = *(const float4*)(wkx + HDIM);
    }

    // ---- epilogue constants: waves 0-3 lanes 0-7 handle one row/chain ----
    float4 b4 = make_float4(0.f, 0.f, 0.f, 0.f);
    int jj = 0;
    if (lane < 8) {
        jj = (jblk << 5) + (lane << 2);
        b4 = *(const float4*)(bias + jj);
    }

    // ---- staging lane maps (4 rows/chain: lane covers rows sbb, sbb+2) ----
    const int sbb = lane >> 5;                 // row parity (0/1)
    const int sko = (lane & 31) << 2;          // k-offset within slice
    float* hdA = htA + (wave << 9) + (sbb << 7) + sko;
    float* hdB = htB + (wave << 9) + (sbb << 7) + sko;
    const int xr = lane >> 4;                  // x row 0..3
    const int xco = lane & 15;                 // x col within 16-slice
    float* xdA = hxA + (wave << 6) + (xr << 4) + xco;
    float* xdB = hxB + (wave << 6) + (xr << 4) + xco;
    const float* hbA = htA + (wave << 9);
    const float* hbB = htB + (wave << 9);
    const float* xbA = hxA + (wave << 6);
    const float* xbB = hxB + (wave << 6);

    // ---- prefetch x slices for t=0 (plain cached loads, x read-only) ----
    float xvA = x[(size_t)(b0 + xr) * IDIM + (wave << 4) + xco];
    float xvB = x[(size_t)(b0 + 4 + xr) * IDIM + (wave << 4) + xco];

    for (int t = 0; t < T_STEPS; ++t) {
        // ================= chain A (rows b0..b0+3) =================
        *xdA = xvA;
        if (t == 0) {
            const float* p = h0 + (size_t)(b0 + sbb) * HDIM + krec + sko;
            *(float4*)(hdA)       = *(const float4*)(p);
            *(float4*)(hdA + 256) = *(const float4*)(p + 2 * HDIM);
        } else {
            const float* p = out + ((size_t)(t - 1) * BATCH + b0 + sbb) * HDIM
                             + krec + sko;
            float4 a, b;
            do { sc_load2x4(p, p + 2 * HDIM, a, b); }
            while (__any((int)(chk4(a) | chk4(b))));
            *(float4*)(hdA)       = a;
            *(float4*)(hdA + 256) = b;
        }
        if (t + 1 < T_STEPS)
            xvA = x[((size_t)(t + 1) * BATCH + b0 + xr) * IDIM + (wave << 4) + xco];

        {
            float4 acc[NB];
            #pragma unroll
            for (int bb = 0; bb < NB; ++bb) acc[bb] = make_float4(0.f, 0.f, 0.f, 0.f);
            #pragma unroll
            for (int i = 0; i < 4; ++i) {
                const int ko = ((i << 3) + ksub) << 2;
                const float4 w0 = Wv[i * 4 + 0], w1 = Wv[i * 4 + 1];
                const float4 w2 = Wv[i * 4 + 2], w3 = Wv[i * 4 + 3];
                #pragma unroll
                for (int bb = 0; bb < NB; ++bb) {
                    float4 h4 = *(const float4*)(hbA + (bb << 7) + ko);
                    acc[bb].x = fmaf(w0.x, h4.x, acc[bb].x);
                    acc[bb].y = fmaf(w0.y, h4.x, acc[bb].y);
                    acc[bb].z = fmaf(w0.z, h4.x, acc[bb].z);
                    acc[bb].w = fmaf(w0.w, h4.x, acc[bb].w);
                    acc[bb].x = fmaf(w1.x, h4.y, acc[bb].x);
                    acc[bb].y = fmaf(w1.y, h4.y, acc[bb].y);
                    acc[bb].z = fmaf(w1.z, h4.y, acc[bb].z);
                    acc[bb].w = fmaf(w1.w, h4.y, acc[bb].w);
                    acc[bb].x = fmaf(w2.x, h4.z, acc[bb].x);
                    acc[bb].y = fmaf(w2.y, h4.z, acc[bb].y);
                    acc[bb].z = fmaf(w2.z, h4.z, acc[bb].z);
                    acc[bb].w = fmaf(w2.w, h4.z, acc[bb].w);
                    acc[bb].x = fmaf(w3.x, h4.w, acc[bb].x);
                    acc[bb].y = fmaf(w3.y, h4.w, acc[bb].y);
                    acc[bb].z = fmaf(w3.z, h4.w, acc[bb].z);
                    acc[bb].w = fmaf(w3.w, h4.w, acc[bb].w);
                }
            }
            #pragma unroll
            for (int bb = 0; bb < NB; ++bb) {
                float2 hx = *(const float2*)(xbA + (bb << 4) + (ksub << 1));
                acc[bb].x = fmaf(Wv[16].x, hx.x, acc[bb].x);
                acc[bb].y = fmaf(Wv[16].y, hx.x, acc[bb].y);
                acc[bb].z = fmaf(Wv[16].z, hx.x, acc[bb].z);
                acc[bb].w = fmaf(Wv[16].w, hx.x, acc[bb].w);
                acc[bb].x = fmaf(Wv[17].x, hx.y, acc[bb].x);
                acc[bb].y = fmaf(Wv[17].y, hx.y, acc[bb].y);
                acc[bb].z = fmaf(Wv[17].z, hx.y, acc[bb].z);
                acc[bb].w = fmaf(Wv[17].w, hx.y, acc[bb].w);
            }
            #pragma unroll
            for (int bb = 0; bb < NB; ++bb) {
                acc[bb].x += __shfl_xor(acc[bb].x, 8);
                acc[bb].y += __shfl_xor(acc[bb].y, 8);
                acc[bb].z += __shfl_xor(acc[bb].z, 8);
                acc[bb].w += __shfl_xor(acc[bb].w, 8);
                acc[bb].x += __shfl_xor(acc[bb].x, 16);
                acc[bb].y += __shfl_xor(acc[bb].y, 16);
                acc[bb].z += __shfl_xor(acc[bb].z, 16);
                acc[bb].w += __shfl_xor(acc[bb].w, 16);
                acc[bb].x += __shfl_xor(acc[bb].x, 32);
                acc[bb].y += __shfl_xor(acc[bb].y, 32);
                acc[bb].z += __shfl_xor(acc[bb].z, 32);
                acc[bb].w += __shfl_xor(acc[bb].w, 32);
            }
            if (ksub == 0) {
                #pragma unroll
                for (int bb = 0; bb < NB; ++bb)
                    redA[((wave << 3) + jq) * 5 + bb] = acc[bb];
            }
        }
        __syncthreads();                               // redA(t) complete
        if (wave < 4 && lane < 8) {
            float4 s = make_float4(0.f, 0.f, 0.f, 0.f);
            #pragma unroll
            for (int w = 0; w < 8; ++w) {
                float4 r = redA[((w << 3) + lane) * 5 + wave];
                s.x += r.x; s.y += r.y; s.z += r.z; s.w += r.w;
            }
            float4 o;
            o.x = tanhf(s.x + b4.x);
            o.y = tanhf(s.y + b4.y);
            o.z = tanhf(s.z + b4.z);
            o.w = tanhf(s.w + b4.w);
            sc_store4_nodrain(out + ((size_t)t * BATCH + b0 + wave) * HDIM + jj, o);
            if (t == T_STEPS - 1)
                *(float4*)(hfin + (size_t)(b0 + wave) * HDIM + jj) = o;
        }

        // ================= chain B (rows b0+4..b0+7) =================
        *xdB = xvB;
        if (t == 0) {
            const float* p = h0 + (size_t)(b0 + 4 + sbb) * HDIM + krec + sko;
            *(float4*)(hdB)       = *(const float4*)(p);
            *(float4*)(hdB + 256) = *(const float4*)(p + 2 * HDIM);
        } else {
            const float* p = out + ((size_t)(t - 1) * BATCH + b0 + 4 + sbb) * HDIM
                             + krec + sko;
            float4 a, b;
            do { sc_load2x4(p, p + 2 * HDIM, a, b); }
            while (__any((int)(chk4(a) | chk4(b))));
            *(float4*)(hdB)       = a;
            *(float4*)(hdB + 256) = b;
        }
        if (t + 1 < T_STEPS)
            xvB = x[((size_t)(t + 1) * BATCH + b0 + 4 + xr) * IDIM
                    + (wave << 4) + xco];

        {
            float4 acc[NB];
            #pragma unroll
            for (int bb = 0; bb < NB; ++bb) acc[bb] = make_float4(0.f, 0.f, 0.f, 0.f);
            #pragma unroll
            for (int i = 0; i < 4; ++i) {
                const int ko = ((i << 3) + ksub) << 2;
                const float4 w0 = Wv[i * 4 + 0], w1 = Wv[i * 4 + 1];
                const float4 w2 = Wv[i * 4 + 2], w3 = Wv[i * 4 + 3];
                #pragma unroll
                for (int bb = 0; bb < NB; ++bb) {
                    float4 h4 = *(const float4*)(hbB + (bb << 7) + ko);
                    acc[bb].x = fmaf(w0.x, h4.x, acc[bb].x);
                    acc[bb].y = fmaf(w0.y, h4.x, acc[bb].y);
                    acc[bb].z = fmaf(w0.z, h4.x, acc[bb].z);
                    acc[bb].w = fmaf(w0.w, h4.x, acc[bb].w);
                    acc[bb].x = fmaf(w1.x, h4.y, acc[bb].x);
                    acc[bb].y = fmaf(w1.y, h4.y, acc[bb].y);
                    acc[bb].z = fmaf(w1.z, h4.y, acc[bb].z);
                    acc[bb].w = fmaf(w1.w, h4.y, acc[bb].w);
                    acc[bb].x = fmaf(w2.x, h4.z, acc[bb].x);
                    acc[bb].y = fmaf(w2.y, h4.z, acc[bb].y);
                    acc[bb].z = fmaf(w2.z, h4.z, acc[bb].z);
                    acc[bb].w = fmaf(w2.w, h4.z, acc[bb].w);
                    acc[bb].x = fmaf(w3.x, h4.w, acc[bb].x);
                    acc[bb].y = fmaf(w3.y, h4.w, acc[bb].y);
                    acc[bb].z = fmaf(w3.z, h4.w, acc[bb].z);
                    acc[bb].w = fmaf(w3.w, h4.w, acc[bb].w);
                }
            }
            #pragma unroll
            for (int bb = 0; bb < NB; ++bb) {
                float2 hx = *(const float2*)(xbB + (bb << 4) + (ksub << 1));
                acc[bb].x = fmaf(Wv[16].x, hx.x, acc[bb].x);
                acc[bb].y = fmaf(Wv[16].y, hx.x, acc[bb].y);
                acc[bb].z = fmaf(Wv[16].z, hx.x, acc[bb].z);
                acc[bb].w = fmaf(Wv[16].w, hx.x, acc[bb].w);
                acc[bb].x = fmaf(Wv[17].x, hx.y, acc[bb].x);
                acc[bb].y = fmaf(Wv[17].y, hx.y, acc[bb].y);
                acc[bb].z = fmaf(Wv[17].z, hx.y, acc[bb].z);
                acc[bb].w = fmaf(Wv[17].w, hx.y, acc[bb].w);
            }
            #pragma unroll
            for (int bb = 0; bb < NB; ++bb) {
                acc[bb].x += __shfl_xor(acc[bb].x, 8);
                acc[bb].y += __shfl_xor(acc[bb].y, 8);
                acc[bb].z += __shfl_xor(acc[bb].z, 8);
                acc[bb].w += __shfl_xor(acc[bb].w, 8);
                acc[bb].x += __shfl_xor(acc[bb].x, 16);
                acc[bb].y += __shfl_xor(acc[bb].y, 16);
                acc[bb].z += __shfl_xor(acc[bb].z, 16);
                acc[bb].w += __shfl_xor(acc[bb].w, 16);
                acc[bb].x += __shfl_xor(acc[bb].x, 32);
                acc[bb].y += __shfl_xor(acc[bb].y, 32);
                acc[bb].z += __shfl_xor(acc[bb].z, 32);
                acc[bb].w += __shfl_xor(acc[bb].w, 32);
            }
            if (ksub == 0) {
                #pragma unroll
                for (int bb = 0; bb < NB; ++bb)
                    redB[((wave << 3) + jq) * 5 + bb] = acc[bb];
            }
        }
        __syncthreads();                               // redB(t) complete
        if (wave < 4 && lane < 8) {
            float4 s = make_float4(0.f, 0.f, 0.f, 0.f);
            #pragma unroll
            for (int w = 0; w < 8; ++w) {
                float4 r = redB[((w << 3) + lane) * 5 + wave];
                s.x += r.x; s.y += r.y; s.z += r.z; s.w += r.w;
            }
            float4 o;
            o.x = tanhf(s.x + b4.x);
            o.y = tanhf(s.y + b4.y);
            o.z = tanhf(s.z + b4.z);
            o.w = tanhf(s.w + b4.w);
            sc_store4_nodrain(out + ((size_t)t * BATCH + b0 + 4 + wave) * HDIM + jj, o);
            if (t == T_STEPS - 1)
                *(float4*)(hfin + (size_t)(b0 + 4 + wave) * HDIM + jj) = o;
        }
    }
}

extern "C" void kernel_launch(void* const* d_in, const int* in_sizes, int n_in,
                              void* d_out, int out_size, void* d_ws, size_t ws_size,
                              hipStream_t stream) {
    const float* x    = (const float*)d_in[0];
    const float* h0   = (const float*)d_in[1];
    const float* w_ih = (const float*)d_in[2];   // [1024][128]
    const float* w_hh = (const float*)d_in[3];   // [1024][1024]
    const float* bias = (const float*)d_in[4];   // [1024]
    float* out = (float*)d_out;

    char* ws = (char*)d_ws;
    float* WT = (float*)ws;                      // [1152][1024] = 4.72 MB

    // poison the polled region: byte 0x7F -> dword 0x7F7F7F7F = 3.4e38,
    // unreachable by tanh. Stream-ordered; re-arms on every replay.
    (void)hipMemsetAsync(out, 0x7F,
                         (size_t)T_STEPS * BATCH * HDIM * sizeof(float), stream);
    transpose_f32<<<256, 256, 0, stream>>>(w_hh, WT, HDIM, HDIM);
    transpose_f32<<<32, 256, 0, stream>>>(w_ih, WT + (size_t)HDIM * HDIM, HDIM, IDIM);
    esn_persistent<<<NWG, 512, 0, stream>>>(x, h0, WT, bias,
                                            out, out + (size_t)T_STEPS * BATCH * HDIM);
}